// Round 7
// baseline (531.163 us; speedup 1.0000x reference)
//
#include <hip/hip_runtime.h>
#include <stdint.h>

typedef unsigned short u16;
typedef unsigned int   u32;
typedef __bf16 bf16x8 __attribute__((ext_vector_type(8)));
typedef float  f32x4  __attribute__((ext_vector_type(4)));
typedef u32    u32x4  __attribute__((ext_vector_type(4)));

#define SQL  1024
#define SKV  2048
#define DQ   512
#define NH   8
#define DH   64
#define NEGC (-1e9f)
#define SCALEC 0.125f

// ---- d_ws layout (u16 elements), total 15,597,568 u16 = 31.2 MB ----
#define OFF_QB  0ull
#define OFF_QP  2097152ull
#define OFF_KP  4194304ull
#define OFF_VPT 8388608ull
#define OFF_AP  12582912ull
#define OFF_BQ  14680064ull
#define OFF_BK  14942208ull
#define OFF_BV  15204352ull
#define OFF_BO  15466496ull
#define WS_NEED_BYTES (15597568ull * 2ull)

__device__ __forceinline__ u16 f2bf(float f) {
  u32 u = __float_as_uint(f);
  u32 r = u + 0x7fffu + ((u >> 16) & 1u);   // RNE
  return (u16)(r >> 16);
}
__device__ __forceinline__ float bf2f(u16 h) {
  return __uint_as_float(((u32)h) << 16);
}
__device__ __forceinline__ bf16x8 ld16(const u16* p) {
  return __builtin_bit_cast(bf16x8, *(const u32x4*)p);
}
__device__ __forceinline__ f32x4 MFMA(bf16x8 a, bf16x8 b, f32x4 c) {
  return __builtin_amdgcn_mfma_f32_16x16x32_bf16(a, b, c, 0, 0, 0);
}
__device__ __forceinline__ void cvt8(const float* src, u16* dst, int t) {
  f32x4 a = ((const f32x4*)src)[2 * t], b = ((const f32x4*)src)[2 * t + 1];
  u32x4 o;
  o[0] = (u32)f2bf(a[0]) | ((u32)f2bf(a[1]) << 16);
  o[1] = (u32)f2bf(a[2]) | ((u32)f2bf(a[3]) << 16);
  o[2] = (u32)f2bf(b[0]) | ((u32)f2bf(b[1]) << 16);
  o[3] = (u32)f2bf(b[2]) | ((u32)f2bf(b[3]) << 16);
  *(u32x4*)(dst + 8 * t) = o;
}
__device__ __forceinline__ float wmaxf(float v) {
#pragma unroll
  for (int o = 1; o < 64; o <<= 1) v = fmaxf(v, __shfl_xor(v, o));
  return v;
}
__device__ __forceinline__ float wsumf(float v) {
#pragma unroll
  for (int o = 1; o < 64; o <<= 1) v += __shfl_xor(v, o);
  return v;
}

// ---------------- f32 code marker (now visible: real f32 store) ----------------
__global__ void k_markf(float* outp, float val) {
  if (threadIdx.x == 0 && blockIdx.x == 0) outp[0] = val;
}

// ---------------- f32 -> bf16 conversions ----------------
__global__ __launch_bounds__(256) void k_conv_x(
    const float* __restrict__ Q, const float* __restrict__ K, const float* __restrict__ V,
    u16* __restrict__ Qb, u16* __restrict__ Kb, u16* __restrict__ Vb)
{
  int t = blockIdx.x * 256 + threadIdx.x;
  if (t < 262144)       cvt8(Q, Qb, t);
  else if (t < 786432)  cvt8(K, Kb, t - 262144);
  else                  cvt8(V, Vb, t - 786432);
}

__global__ __launch_bounds__(256) void k_conv_w(
    const float* __restrict__ Wq, const float* __restrict__ Wk,
    const float* __restrict__ Wv, const float* __restrict__ Wo,
    u16* __restrict__ BQ, u16* __restrict__ BK, u16* __restrict__ BV, u16* __restrict__ BO)
{
  int t = blockIdx.x * 256 + threadIdx.x;
  if (t < 32768)        cvt8(Wq, BQ, t);
  else if (t < 65536)   cvt8(Wk, BK, t - 32768);
  else if (t < 98304)   cvt8(Wv, BV, t - 65536);
  else                  cvt8(Wo, BO, t - 98304);
}

// ---------------- GEMM: out[m][n] = sum_k A[m][k]*B2[n][k] + bias[n], K=512 ----------------
template <typename OUT_T>
__global__ __launch_bounds__(256) void k_gemm(
    const u16* __restrict__ A, int lda,
    const u16* __restrict__ B2, int ldb,
    const float* __restrict__ bias,
    OUT_T* __restrict__ out, int ldo)
{
  __shared__ u16 As[128 * 72], Bs[128 * 72];
  const int tid = threadIdx.x;
  const int wid = tid >> 6, ln = tid & 63;
  const int l15 = ln & 15, lh = ln >> 4;
  const int m0 = blockIdx.x * 128, n0 = blockIdx.y * 128;
  const int wm = (wid & 1) * 64, wn = (wid >> 1) * 64;

  f32x4 acc[4][4];
#pragma unroll
  for (int mi = 0; mi < 4; ++mi)
#pragma unroll
    for (int ni = 0; ni < 4; ++ni) acc[mi][ni] = (f32x4){0.f, 0.f, 0.f, 0.f};

  for (int k0 = 0; k0 < 512; k0 += 64) {
#pragma unroll
    for (int s5 = 0; s5 < 4; ++s5) {
      int ci = s5 * 256 + tid;
      int row = ci >> 3, kc = ci & 7;
      *(u32x4*)(As + row * 72 + kc * 8) =
          *(const u32x4*)(A + (size_t)(m0 + row) * lda + k0 + kc * 8);
      *(u32x4*)(Bs + row * 72 + kc * 8) =
          *(const u32x4*)(B2 + (size_t)(n0 + row) * ldb + k0 + kc * 8);
    }
    __syncthreads();
    bf16x8 af[4][2], bfr[4][2];
#pragma unroll
    for (int mi = 0; mi < 4; ++mi) {
      int r = wm + mi * 16 + l15;
#pragma unroll
      for (int ks = 0; ks < 2; ++ks)
        af[mi][ks] = ld16(As + r * 72 + (ks * 4 + lh) * 8);
    }
#pragma unroll
    for (int ni = 0; ni < 4; ++ni) {
      int r = wn + ni * 16 + l15;
#pragma unroll
      for (int ks = 0; ks < 2; ++ks)
        bfr[ni][ks] = ld16(Bs + r * 72 + (ks * 4 + lh) * 8);
    }
#pragma unroll
    for (int mi = 0; mi < 4; ++mi)
#pragma unroll
      for (int ni = 0; ni < 4; ++ni) {
        acc[mi][ni] = MFMA(af[mi][0], bfr[ni][0], acc[mi][ni]);
        acc[mi][ni] = MFMA(af[mi][1], bfr[ni][1], acc[mi][ni]);
      }
    __syncthreads();
  }
  float bv[4];
#pragma unroll
  for (int ni = 0; ni < 4; ++ni) bv[ni] = bias[n0 + wn + ni * 16 + l15];
#pragma unroll
  for (int mi = 0; mi < 4; ++mi)
#pragma unroll
    for (int ni = 0; ni < 4; ++ni)
#pragma unroll
      for (int j = 0; j < 4; ++j) {
        float v = acc[mi][ni][j] + bv[ni];
        size_t idx = (size_t)(m0 + wm + mi * 16 + lh * 4 + j) * ldo + n0 + wn + ni * 16 + l15;
        if constexpr (sizeof(OUT_T) == 4) out[idx] = v;
        else                              out[idx] = f2bf(v);
      }
}

// ---------------- VP [8192][512] -> VpT [b][h][64][2048] ----------------
__global__ __launch_bounds__(256) void k_transpose(const u16* __restrict__ Vp, u16* __restrict__ VpT)
{
  __shared__ u16 T[64 * 72];
  const int bh = blockIdx.x, kt = blockIdx.y;
  const int b = bh >> 3, h = bh & 7;
  const int tid = threadIdx.x;
#pragma unroll
  for (int s = 0; s < 2; ++s) {
    int ci = s * 256 + tid;
    int row = ci >> 3, dc = ci & 7;
    *(u32x4*)(T + row * 72 + dc * 8) =
        *(const u32x4*)(Vp + (size_t)(b * 2048 + kt * 64 + row) * 512 + h * 64 + dc * 8);
  }
  __syncthreads();
#pragma unroll
  for (int s = 0; s < 2; ++s) {
    int ci = s * 256 + tid;
    int d = ci >> 3, kc = ci & 7;
    u32x4 v;
#pragma unroll
    for (int i = 0; i < 4; ++i) {
      u32 lo = T[(kc * 8 + 2 * i)     * 72 + d];
      u32 hi = T[(kc * 8 + 2 * i + 1) * 72 + d];
      v[i] = lo | (hi << 16);
    }
    *(u32x4*)(VpT + ((size_t)(b * 8 + h) * 64 + d) * 2048 + kt * 64 + kc * 8) = v;
  }
}

// ---------------- fused attention: weights out in FP32 ----------------
__global__ __launch_bounds__(512) void k_attn(
    const u16* __restrict__ Qp, const u16* __restrict__ Kp, const u16* __restrict__ VpT,
    const float* __restrict__ aff, const int* __restrict__ qbm, const int* __restrict__ kvm,
    float* __restrict__ wout, u16* __restrict__ AP)
{
  __shared__ u16 Plds[8 * 16 * 72];
  const int tid = threadIdx.x;
  const int w = tid >> 6, ln = tid & 63;
  const int l15 = ln & 15, lh = ln >> 4;
  const int b = blockIdx.y, rt = blockIdx.x, h = w;
  const int r0 = rt * 16;
  const int bh = b * NH + h;
  u16* Pl = Plds + w * 16 * 72;

  bf16x8 qa0, qa1;
  {
    const u16* qp = Qp + (size_t)(b * SQL + r0 + l15) * DQ + h * DH + lh * 8;
    qa0 = ld16(qp); qa1 = ld16(qp + 32);
  }

  float m[4], ls[4];
#pragma unroll
  for (int j = 0; j < 4; ++j) { m[j] = -3.0e38f; ls[j] = 0.f; }

  const float* affb = aff + (size_t)b * SQL * SKV;
  const int*   qbb  = qbm + (size_t)b * SQL * SKV;
  const int*   kvb  = kvm + (size_t)b * SKV;

  auto compute_s = [&](int kb, f32x4* s) {
#pragma unroll
    for (int ni = 0; ni < 4; ++ni) {
      const u16* kp = Kp + (size_t)(b * SKV + kb + ni * 16 + l15) * DQ + h * DH + lh * 8;
      bf16x8 k0 = ld16(kp), k1 = ld16(kp + 32);
      f32x4 z = (f32x4){0.f, 0.f, 0.f, 0.f};
      z = MFMA(qa0, k0, z);
      z = MFMA(qa1, k1, z);
      s[ni] = z;
    }
#pragma unroll
    for (int ni = 0; ni < 4; ++ni) {
      const int c = kb + ni * 16 + l15;
      const int km = kvb[c];
#pragma unroll
      for (int j = 0; j < 4; ++j) {
        const int r = r0 + lh * 4 + j;
        const size_t off = (size_t)r * SKV + c;
        float a = affb[off];
        int qm = qbb[off];
        float v = s[ni][j] * SCALEC;
        v = km ? NEGC : v;   // kv mask BEFORE aff (ref order)
        v = v * a;
        v = qm ? NEGC : v;
        s[ni][j] = v;
      }
    }
  };

  // ---- pass A: online m,l ----
  for (int t = 0; t < 32; ++t) {
    f32x4 s[4];
    compute_s(t * 64, s);
#pragma unroll
    for (int j = 0; j < 4; ++j) {
      float mx = fmaxf(fmaxf(s[0][j], s[1][j]), fmaxf(s[2][j], s[3][j]));
      float mn = fmaxf(m[j], mx);
      float sum = __expf(s[0][j] - mn) + __expf(s[1][j] - mn) +
                  __expf(s[2][j] - mn) + __expf(s[3][j] - mn);
      ls[j] = ls[j] * __expf(m[j] - mn) + sum;
      m[j] = mn;
    }
  }
#pragma unroll
  for (int j = 0; j < 4; ++j) {
#pragma unroll
    for (int off = 1; off < 16; off <<= 1) {
      float m2 = __shfl_xor(m[j], off);
      float l2 = __shfl_xor(ls[j], off);
      float mm = fmaxf(m[j], m2);
      ls[j] = ls[j] * __expf(m[j] - mm) + l2 * __expf(m2 - mm);
      m[j] = mm;
    }
  }
  float rl[4];
#pragma unroll
  for (int j = 0; j < 4; ++j) rl[j] = 1.0f / ls[j];

  f32x4 acc[4];
#pragma unroll
  for (int nd = 0; nd < 4; ++nd) acc[nd] = (f32x4){0.f, 0.f, 0.f, 0.f};

  // ---- pass B: recompute s, write f32 weights, PV ----
  for (int t = 0; t < 32; ++t) {
    const int kb = t * 64;
    f32x4 s[4];
    compute_s(kb, s);
#pragma unroll
    for (int ni = 0; ni < 4; ++ni) {
#pragma unroll
      for (int j = 0; j < 4; ++j) {
        float wv = __expf(s[ni][j] - m[j]) * rl[j];
        int r = lh * 4 + j, c = ni * 16 + l15;
        Pl[r * 72 + c] = f2bf(wv);
        wout[((size_t)bh * SQL + r0 + r) * SKV + kb + c] = wv;   // f32 weights out
      }
    }
    asm volatile("s_waitcnt lgkmcnt(0)" ::: "memory");
    bf16x8 pa0, pa1;
    {
      int r = l15;
      pa0 = ld16(Pl + r * 72 + lh * 8);
      pa1 = ld16(Pl + r * 72 + 32 + lh * 8);
    }
#pragma unroll
    for (int nd = 0; nd < 4; ++nd) {
      const u16* vp = VpT + (size_t)(bh * DH + nd * 16 + l15) * SKV + kb + lh * 8;
      bf16x8 v0 = ld16(vp);
      bf16x8 v1 = ld16(vp + 32);
      acc[nd] = MFMA(pa0, v0, acc[nd]);
      acc[nd] = MFMA(pa1, v1, acc[nd]);
    }
  }
#pragma unroll
  for (int nd = 0; nd < 4; ++nd)
#pragma unroll
    for (int j = 0; j < 4; ++j)
      AP[(size_t)(b * SQL + r0 + lh * 4 + j) * DQ + h * DH + nd * 16 + l15] = f2bf(acc[nd][j]);
}

// ---------------- conditional diag: writes f32 code 65536+512*mask ONLY on failure ----------------
// bits: 1=VPT vs V*Wv  2=QP/KP  4=weights row  8=AP row  16=out0 spots
__global__ __launch_bounds__(64) void k_diag(
    const float* Qf, const float* Kf, const float* Vf,
    const float* aff, const int* qbm, const int* kvm,
    const float* Wqf, const float* Wkf, const float* Wvf, const float* Wof, const float* bof,
    const u16* QP, const u16* KP, const u16* VPT, const u16* AP,
    const float* wout, float* outp)
{
  const int ln = threadIdx.x;
  int mask = 0;

  // bit 1: VPT vs V*Wv spots (the previously-unchecked link)
  {
    const int bb = 2, hh = 5;
    int d = ln, kk = (ln * 131) & 2047;
    float r = 0.f;
    for (int k = 0; k < 512; ++k)
      r += bf2f(f2bf(Vf[(size_t)(bb * 2048 + kk) * 512 + k])) *
           bf2f(f2bf(Wvf[(size_t)(hh * 64 + d) * 512 + k]));
    float e = fabsf(r - bf2f(VPT[((size_t)(bb * 8 + hh) * 64 + d) * 2048 + kk]));
    if (wmaxf(e) > 0.05f) mask |= 1;
  }
  // bit 2: QP (lanes<32) / KP (lanes>=32) spots
  {
    float e;
    if (ln < 32) {
      int mi = (ln * 67) & 4095, n = (ln * 37) & 511;
      float r = 0.f;
      for (int k = 0; k < 512; ++k)
        r += bf2f(f2bf(Qf[(size_t)mi * 512 + k])) * bf2f(f2bf(Wqf[(size_t)n * 512 + k]));
      e = fabsf(r - bf2f(QP[(size_t)mi * 512 + n]));
    } else {
      int mi = (ln * 131) & 8191, n = (ln * 37) & 511;
      float r = 0.f;
      for (int k = 0; k < 512; ++k)
        r += bf2f(f2bf(Kf[(size_t)mi * 512 + k])) * bf2f(f2bf(Wkf[(size_t)n * 512 + k]));
      e = fabsf(r - bf2f(KP[(size_t)mi * 512 + n]));
    }
    if (wmaxf(e) > 0.05f) mask |= 2;
  }
  // bits 4/8: one full weights row (f32) + AP row (b=1,h=3,q=517)
  {
    const int bb = 1, hh = 3, qq = 517;
    float s[32];
    float mymax = -3e38f;
    for (int t = 0; t < 32; ++t) {
      int k = ln + t * 64;
      float acc = 0.f;
      for (int d = 0; d < 64; ++d)
        acc += bf2f(QP[(size_t)(bb * 1024 + qq) * 512 + hh * 64 + d]) *
               bf2f(KP[(size_t)(bb * 2048 + k) * 512 + hh * 64 + d]);
      acc *= 0.125f;
      if (kvm[bb * 2048 + k]) acc = NEGC;
      acc *= aff[((size_t)bb * 1024 + qq) * 2048 + k];
      if (qbm[((size_t)bb * 1024 + qq) * 2048 + k]) acc = NEGC;
      s[t] = acc;
      mymax = fmaxf(mymax, acc);
    }
    float M = wmaxf(mymax);
    float psum = 0.f;
    for (int t = 0; t < 32; ++t) psum += __expf(s[t] - M);
    float Dn = wsumf(psum);
    float ew = 0.f;
    for (int t = 0; t < 32; ++t) {
      int k = ln + t * 64;
      float wv = __expf(s[t] - M) / Dn;
      float st = wout[(((size_t)(bb * 8 + hh)) * 1024 + qq) * 2048 + k];
      ew = fmaxf(ew, fabsf(wv - st) - 0.05f * fabsf(wv));
    }
    if (wmaxf(ew) > 3e-5f) mask |= 4;
    float r = 0.f;
    for (int k = 0; k < 2048; ++k)
      r += wout[(((size_t)(bb * 8 + hh)) * 1024 + qq) * 2048 + k] *
           bf2f(VPT[((size_t)(bb * 8 + hh) * 64 + ln) * 2048 + k]);
    float ea = fabsf(r - bf2f(AP[(size_t)(bb * 1024 + qq) * 512 + hh * 64 + ln]));
    if (wmaxf(ea) > 2e-3f) mask |= 8;
  }
  // bit 16: 64 out0 spots
  {
    int mi = (ln * 1237) & 4095, n = (ln * 89) & 255;
    if (mi == 0 && n == 0) n = 1;
    float r = bof[n];
    for (int k = 0; k < 512; ++k)
      r += bf2f(AP[(size_t)mi * 512 + k]) * bf2f(f2bf(Wof[(size_t)n * 512 + k]));
    float e = fabsf(r - outp[(size_t)mi * 256 + n]);
    if (wmaxf(e) > 3e-4f) mask |= 16;
  }
  if (ln == 0 && mask != 0)
    outp[0] = 65536.0f + 512.0f * (float)mask;
}

extern "C" void kernel_launch(void* const* d_in, const int* in_sizes, int n_in,
                              void* d_out, int out_size, void* d_ws, size_t ws_size,
                              hipStream_t stream)
{
  const float* Q   = (const float*)d_in[0];
  const float* K   = (const float*)d_in[1];
  const float* V   = (const float*)d_in[2];
  const float* aff = (const float*)d_in[3];
  const int*   qb  = (const int*)d_in[4];
  const int*   kvm = (const int*)d_in[5];
  const float* Wq  = (const float*)d_in[6];
  const float* bq  = (const float*)d_in[7];
  const float* Wk  = (const float*)d_in[8];
  const float* bk  = (const float*)d_in[9];
  const float* Wv  = (const float*)d_in[10];
  const float* bv  = (const float*)d_in[11];
  const float* Wo  = (const float*)d_in[12];
  const float* bo  = (const float*)d_in[13];
  u16*   ws   = (u16*)d_ws;
  float* outF = (float*)d_out;            // OUTPUT IS FLOAT32 (reference returns f32)
  float* wout = outF + 1048576;           // att_weights region, f32 [4*8*1024*2048]
  u16* Kb = (u16*)wout;                   // u16 scratch inside weights region (dead until k_attn)
  u16* Vb = Kb + 4194304;
  u16* VP = Vb + 4194304;

  const int want[14] = {2097152, 4194304, 4194304, 8388608, 8388608, 8192,
                        262144, 512, 262144, 512, 262144, 512, 131072, 256};
  int bad = (n_in == 14) ? -1 : 14;
  if (bad < 0)
    for (int i = 0; i < 14; ++i)
      if (in_sizes[i] != want[i]) { bad = i; break; }
  if (bad >= 0) { k_markf<<<1, 64, 0, stream>>>(outF, 1024.0f * (160.0f + (float)bad)); return; }
  if (ws_size < WS_NEED_BYTES) { k_markf<<<1, 64, 0, stream>>>(outF, 180224.0f); return; }

  k_conv_x<<<5120, 256, 0, stream>>>(Q, K, V, ws + OFF_QB, Kb, Vb);
  k_conv_w<<<448, 256, 0, stream>>>(Wq, Wk, Wv, Wo, ws + OFF_BQ, ws + OFF_BK, ws + OFF_BV, ws + OFF_BO);
  k_gemm<u16><<<dim3(32, 4), 256, 0, stream>>>(ws + OFF_QB, 512, ws + OFF_BQ, 512, bq, ws + OFF_QP, 512);
  k_gemm<u16><<<dim3(64, 4), 256, 0, stream>>>(Kb, 512, ws + OFF_BK, 512, bk, ws + OFF_KP, 512);
  k_gemm<u16><<<dim3(64, 4), 256, 0, stream>>>(Vb, 512, ws + OFF_BV, 512, bv, VP, 512);
  k_transpose<<<dim3(32, 32), 256, 0, stream>>>(VP, ws + OFF_VPT);
  k_attn<<<dim3(64, 4), 512, 0, stream>>>(ws + OFF_QP, ws + OFF_KP, ws + OFF_VPT,
                                          aff, qb, kvm, wout, ws + OFF_AP);
  k_gemm<float><<<dim3(32, 2), 256, 0, stream>>>(ws + OFF_AP, 512, ws + OFF_BO, 512, bo, outF, 256);
  k_diag<<<1, 64, 0, stream>>>(Q, K, V, aff, qb, kvm, Wq, Wk, Wv, Wo, bo,
                               ws + OFF_QP, ws + OFF_KP, ws + OFF_VPT, ws + OFF_AP,
                               wout, outF);
}

// Round 8
// 357.492 us; speedup vs baseline: 1.4858x; 1.4858x over previous
//
#include <hip/hip_runtime.h>
#include <stdint.h>

typedef unsigned short u16;
typedef unsigned int   u32;
typedef __bf16 bf16x8 __attribute__((ext_vector_type(8)));
typedef float  f32x4  __attribute__((ext_vector_type(4)));
typedef u32    u32x4  __attribute__((ext_vector_type(4)));

#define SQL  1024
#define SKV  2048
#define DQ   512
#define NH   8
#define DH   64
#define NEGC (-1e9f)
#define SCALEC 0.125f

// ---- d_ws layout (u16 elements), total 15,597,568 u16 = 31.2 MB ----
#define OFF_QB  0ull
#define OFF_QP  2097152ull
#define OFF_KP  4194304ull
#define OFF_VPT 8388608ull
#define OFF_AP  12582912ull
#define OFF_BQ  14680064ull
#define OFF_BK  14942208ull
#define OFF_BV  15204352ull
#define OFF_BO  15466496ull
#define WS_NEED_BYTES (15597568ull * 2ull)

__device__ __forceinline__ u16 f2bf(float f) {
  u32 u = __float_as_uint(f);
  u32 r = u + 0x7fffu + ((u >> 16) & 1u);   // RNE
  return (u16)(r >> 16);
}
__device__ __forceinline__ float bf2f(u16 h) {
  return __uint_as_float(((u32)h) << 16);
}
__device__ __forceinline__ bf16x8 ld16(const u16* p) {
  return __builtin_bit_cast(bf16x8, *(const u32x4*)p);
}
__device__ __forceinline__ f32x4 MFMA(bf16x8 a, bf16x8 b, f32x4 c) {
  return __builtin_amdgcn_mfma_f32_16x16x32_bf16(a, b, c, 0, 0, 0);
}
__device__ __forceinline__ void cvt8(const float* src, u16* dst, int t) {
  f32x4 a = ((const f32x4*)src)[2 * t], b = ((const f32x4*)src)[2 * t + 1];
  u32x4 o;
  o[0] = (u32)f2bf(a[0]) | ((u32)f2bf(a[1]) << 16);
  o[1] = (u32)f2bf(a[2]) | ((u32)f2bf(a[3]) << 16);
  o[2] = (u32)f2bf(b[0]) | ((u32)f2bf(b[1]) << 16);
  o[3] = (u32)f2bf(b[2]) | ((u32)f2bf(b[3]) << 16);
  *(u32x4*)(dst + 8 * t) = o;
}

// ---------------- f32 code marker ----------------
__global__ void k_markf(float* outp, float val) {
  if (threadIdx.x == 0 && blockIdx.x == 0) outp[0] = val;
}

// ---------------- f32 -> bf16 conversions ----------------
__global__ __launch_bounds__(256) void k_conv_x(
    const float* __restrict__ Q, const float* __restrict__ K, const float* __restrict__ V,
    u16* __restrict__ Qb, u16* __restrict__ Kb, u16* __restrict__ Vb)
{
  int t = blockIdx.x * 256 + threadIdx.x;
  if (t < 262144)       cvt8(Q, Qb, t);
  else if (t < 786432)  cvt8(K, Kb, t - 262144);
  else                  cvt8(V, Vb, t - 786432);
}

__global__ __launch_bounds__(256) void k_conv_w(
    const float* __restrict__ Wq, const float* __restrict__ Wk,
    const float* __restrict__ Wv, const float* __restrict__ Wo,
    u16* __restrict__ BQ, u16* __restrict__ BK, u16* __restrict__ BV, u16* __restrict__ BO)
{
  int t = blockIdx.x * 256 + threadIdx.x;
  if (t < 32768)        cvt8(Wq, BQ, t);
  else if (t < 65536)   cvt8(Wk, BK, t - 32768);
  else if (t < 98304)   cvt8(Wv, BV, t - 65536);
  else                  cvt8(Wo, BO, t - 98304);
}

// ---------------- GEMM: out[m][n] = sum_k A[m][k]*B2[n][k] + bias[n], K=512 ----------------
template <typename OUT_T>
__global__ __launch_bounds__(256) void k_gemm(
    const u16* __restrict__ A, int lda,
    const u16* __restrict__ B2, int ldb,
    const float* __restrict__ bias,
    OUT_T* __restrict__ out, int ldo)
{
  __shared__ u16 As[128 * 72], Bs[128 * 72];
  const int tid = threadIdx.x;
  const int wid = tid >> 6, ln = tid & 63;
  const int l15 = ln & 15, lh = ln >> 4;
  const int m0 = blockIdx.x * 128, n0 = blockIdx.y * 128;
  const int wm = (wid & 1) * 64, wn = (wid >> 1) * 64;

  f32x4 acc[4][4];
#pragma unroll
  for (int mi = 0; mi < 4; ++mi)
#pragma unroll
    for (int ni = 0; ni < 4; ++ni) acc[mi][ni] = (f32x4){0.f, 0.f, 0.f, 0.f};

  for (int k0 = 0; k0 < 512; k0 += 64) {
#pragma unroll
    for (int s5 = 0; s5 < 4; ++s5) {
      int ci = s5 * 256 + tid;
      int row = ci >> 3, kc = ci & 7;
      *(u32x4*)(As + row * 72 + kc * 8) =
          *(const u32x4*)(A + (size_t)(m0 + row) * lda + k0 + kc * 8);
      *(u32x4*)(Bs + row * 72 + kc * 8) =
          *(const u32x4*)(B2 + (size_t)(n0 + row) * ldb + k0 + kc * 8);
    }
    __syncthreads();
    bf16x8 af[4][2], bfr[4][2];
#pragma unroll
    for (int mi = 0; mi < 4; ++mi) {
      int r = wm + mi * 16 + l15;
#pragma unroll
      for (int ks = 0; ks < 2; ++ks)
        af[mi][ks] = ld16(As + r * 72 + (ks * 4 + lh) * 8);
    }
#pragma unroll
    for (int ni = 0; ni < 4; ++ni) {
      int r = wn + ni * 16 + l15;
#pragma unroll
      for (int ks = 0; ks < 2; ++ks)
        bfr[ni][ks] = ld16(Bs + r * 72 + (ks * 4 + lh) * 8);
    }
#pragma unroll
    for (int mi = 0; mi < 4; ++mi)
#pragma unroll
      for (int ni = 0; ni < 4; ++ni) {
        acc[mi][ni] = MFMA(af[mi][0], bfr[ni][0], acc[mi][ni]);
        acc[mi][ni] = MFMA(af[mi][1], bfr[ni][1], acc[mi][ni]);
      }
    __syncthreads();
  }
  float bv[4];
#pragma unroll
  for (int ni = 0; ni < 4; ++ni) bv[ni] = bias[n0 + wn + ni * 16 + l15];
#pragma unroll
  for (int mi = 0; mi < 4; ++mi)
#pragma unroll
    for (int ni = 0; ni < 4; ++ni)
#pragma unroll
      for (int j = 0; j < 4; ++j) {
        float v = acc[mi][ni][j] + bv[ni];
        size_t idx = (size_t)(m0 + wm + mi * 16 + lh * 4 + j) * ldo + n0 + wn + ni * 16 + l15;
        if constexpr (sizeof(OUT_T) == 4) out[idx] = v;
        else                              out[idx] = f2bf(v);
      }
}

// ---------------- VP [8192][512] -> VpT [b][h][64][2048] ----------------
__global__ __launch_bounds__(256) void k_transpose(const u16* __restrict__ Vp, u16* __restrict__ VpT)
{
  __shared__ u16 T[64 * 72];
  const int bh = blockIdx.x, kt = blockIdx.y;
  const int b = bh >> 3, h = bh & 7;
  const int tid = threadIdx.x;
#pragma unroll
  for (int s = 0; s < 2; ++s) {
    int ci = s * 256 + tid;
    int row = ci >> 3, dc = ci & 7;
    *(u32x4*)(T + row * 72 + dc * 8) =
        *(const u32x4*)(Vp + (size_t)(b * 2048 + kt * 64 + row) * 512 + h * 64 + dc * 8);
  }
  __syncthreads();
#pragma unroll
  for (int s = 0; s < 2; ++s) {
    int ci = s * 256 + tid;
    int d = ci >> 3, kc = ci & 7;
    u32x4 v;
#pragma unroll
    for (int i = 0; i < 4; ++i) {
      u32 lo = T[(kc * 8 + 2 * i)     * 72 + d];
      u32 hi = T[(kc * 8 + 2 * i + 1) * 72 + d];
      v[i] = lo | (hi << 16);
    }
    *(u32x4*)(VpT + ((size_t)(b * 8 + h) * 64 + d) * 2048 + kt * 64 + kc * 8) = v;
  }
}

// ---------------- fused attention, 2-way KV-split ----------------
// grid (rt=64, b=4, hg=2); block 512 = 8 waves.
// wave w: head = hg*4 + (w&3), kvhalf = w>>2, covers kv [kvhalf*1024, +1024)
__global__ __launch_bounds__(512, 4) void k_attn(
    const u16* __restrict__ Qp, const u16* __restrict__ Kp, const u16* __restrict__ VpT,
    const float* __restrict__ aff, const int* __restrict__ qbm, const int* __restrict__ kvm,
    float* __restrict__ wout, u16* __restrict__ AP)
{
  __shared__ u16 Plds[8 * 16 * 72];
  __shared__ float Ml[8][16], Ls[8][16];
  __shared__ float AccX[4][64][16];
  const int tid = threadIdx.x;
  const int w = tid >> 6, ln = tid & 63;
  const int l15 = ln & 15, lh = ln >> 4;
  const int b = blockIdx.y, rt = blockIdx.x, hg = blockIdx.z;
  const int h = hg * 4 + (w & 3);
  const int kvhalf = w >> 2;
  const int kv0 = kvhalf * 1024;
  const int r0 = rt * 16;
  const int bh = b * NH + h;
  u16* Pl = Plds + w * 16 * 72;

  bf16x8 qa0, qa1;
  {
    const u16* qp = Qp + (size_t)(b * SQL + r0 + l15) * DQ + h * DH + lh * 8;
    qa0 = ld16(qp); qa1 = ld16(qp + 32);
  }

  float m[4], ls[4];
#pragma unroll
  for (int j = 0; j < 4; ++j) { m[j] = -3.0e38f; ls[j] = 0.f; }

  const float* affb = aff + (size_t)b * SQL * SKV;
  const int*   qbb  = qbm + (size_t)b * SQL * SKV;
  const int*   kvb  = kvm + (size_t)b * SKV;

  auto compute_s = [&](int kb, f32x4* s) {
#pragma unroll
    for (int ni = 0; ni < 4; ++ni) {
      const u16* kp = Kp + (size_t)(b * SKV + kb + ni * 16 + l15) * DQ + h * DH + lh * 8;
      bf16x8 k0 = ld16(kp), k1 = ld16(kp + 32);
      f32x4 z = (f32x4){0.f, 0.f, 0.f, 0.f};
      z = MFMA(qa0, k0, z);
      z = MFMA(qa1, k1, z);
      s[ni] = z;
    }
#pragma unroll
    for (int ni = 0; ni < 4; ++ni) {
      const int c = kb + ni * 16 + l15;
      const int km = kvb[c];
#pragma unroll
      for (int j = 0; j < 4; ++j) {
        const int r = r0 + lh * 4 + j;
        const size_t off = (size_t)r * SKV + c;
        float a = affb[off];
        int qm = qbb[off];
        float v = s[ni][j] * SCALEC;
        v = km ? NEGC : v;   // kv mask BEFORE aff (ref order)
        v = v * a;
        v = qm ? NEGC : v;
        s[ni][j] = v;
      }
    }
  };

  // ---- pass A: online m,l over this wave's 16 k-blocks ----
  for (int t = 0; t < 16; ++t) {
    f32x4 s[4];
    compute_s(kv0 + t * 64, s);
#pragma unroll
    for (int j = 0; j < 4; ++j) {
      float mx = fmaxf(fmaxf(s[0][j], s[1][j]), fmaxf(s[2][j], s[3][j]));
      float mn = fmaxf(m[j], mx);
      float sum = __expf(s[0][j] - mn) + __expf(s[1][j] - mn) +
                  __expf(s[2][j] - mn) + __expf(s[3][j] - mn);
      ls[j] = ls[j] * __expf(m[j] - mn) + sum;
      m[j] = mn;
    }
  }
  // intra-wave reduce within 16-lane col groups
#pragma unroll
  for (int j = 0; j < 4; ++j) {
#pragma unroll
    for (int off = 1; off < 16; off <<= 1) {
      float m2 = __shfl_xor(m[j], off);
      float l2 = __shfl_xor(ls[j], off);
      float mm = fmaxf(m[j], m2);
      ls[j] = ls[j] * __expf(m[j] - mm) + l2 * __expf(m2 - mm);
      m[j] = mm;
    }
  }
  // cross-wave (kv-half) combine via LDS
  if (l15 == 0) {
#pragma unroll
    for (int j = 0; j < 4; ++j) { Ml[w][lh * 4 + j] = m[j]; Ls[w][lh * 4 + j] = ls[j]; }
  }
  __syncthreads();
  {
    const int pw = w ^ 4;
#pragma unroll
    for (int j = 0; j < 4; ++j) {
      float m2 = Ml[pw][lh * 4 + j], l2 = Ls[pw][lh * 4 + j];
      float mm = fmaxf(m[j], m2);
      ls[j] = ls[j] * __expf(m[j] - mm) + l2 * __expf(m2 - mm);
      m[j] = mm;
    }
  }
  float rl[4];
#pragma unroll
  for (int j = 0; j < 4; ++j) rl[j] = 1.0f / ls[j];

  f32x4 acc[4];
#pragma unroll
  for (int nd = 0; nd < 4; ++nd) acc[nd] = (f32x4){0.f, 0.f, 0.f, 0.f};

  // ---- pass B: recompute s, write f32 weights, partial PV ----
  for (int t = 0; t < 16; ++t) {
    const int kb = kv0 + t * 64;
    f32x4 s[4];
    compute_s(kb, s);
#pragma unroll
    for (int ni = 0; ni < 4; ++ni) {
#pragma unroll
      for (int j = 0; j < 4; ++j) {
        float wv = __expf(s[ni][j] - m[j]) * rl[j];
        int r = lh * 4 + j, c = ni * 16 + l15;
        Pl[r * 72 + c] = f2bf(wv);
        wout[((size_t)bh * SQL + r0 + r) * SKV + kb + c] = wv;
      }
    }
    asm volatile("s_waitcnt lgkmcnt(0)" ::: "memory");
    bf16x8 pa0, pa1;
    {
      int r = l15;
      pa0 = ld16(Pl + r * 72 + lh * 8);
      pa1 = ld16(Pl + r * 72 + 32 + lh * 8);
    }
#pragma unroll
    for (int nd = 0; nd < 4; ++nd) {
      const u16* vp = VpT + (size_t)(bh * DH + nd * 16 + l15) * SKV + kb + lh * 8;
      bf16x8 v0 = ld16(vp);
      bf16x8 v1 = ld16(vp + 32);
      acc[nd] = MFMA(pa0, v0, acc[nd]);
      acc[nd] = MFMA(pa1, v1, acc[nd]);
    }
  }

  // ---- combine partial PV across kv-halves, write AP ----
  if (w >= 4) {
#pragma unroll
    for (int nd = 0; nd < 4; ++nd)
      *(f32x4*)&AccX[w - 4][ln][nd * 4] = acc[nd];
  }
  __syncthreads();
  if (w < 4) {
#pragma unroll
    for (int nd = 0; nd < 4; ++nd) {
      f32x4 o = *(const f32x4*)&AccX[w][ln][nd * 4];
#pragma unroll
      for (int j = 0; j < 4; ++j)
        AP[(size_t)(b * SQL + r0 + lh * 4 + j) * DQ + h * DH + nd * 16 + l15] =
            f2bf(acc[nd][j] + o[j]);
    }
  }
}

extern "C" void kernel_launch(void* const* d_in, const int* in_sizes, int n_in,
                              void* d_out, int out_size, void* d_ws, size_t ws_size,
                              hipStream_t stream)
{
  const float* Q   = (const float*)d_in[0];
  const float* K   = (const float*)d_in[1];
  const float* V   = (const float*)d_in[2];
  const float* aff = (const float*)d_in[3];
  const int*   qb  = (const int*)d_in[4];
  const int*   kvm = (const int*)d_in[5];
  const float* Wq  = (const float*)d_in[6];
  const float* bq  = (const float*)d_in[7];
  const float* Wk  = (const float*)d_in[8];
  const float* bk  = (const float*)d_in[9];
  const float* Wv  = (const float*)d_in[10];
  const float* bv  = (const float*)d_in[11];
  const float* Wo  = (const float*)d_in[12];
  const float* bo  = (const float*)d_in[13];
  u16*   ws   = (u16*)d_ws;
  float* outF = (float*)d_out;            // f32 output (reference returns f32)
  float* wout = outF + 1048576;           // att_weights region, f32
  u16* Kb = (u16*)wout;                   // u16 scratch inside weights region (dead until k_attn)
  u16* Vb = Kb + 4194304;
  u16* VP = Vb + 4194304;

  const int want[14] = {2097152, 4194304, 4194304, 8388608, 8388608, 8192,
                        262144, 512, 262144, 512, 262144, 512, 131072, 256};
  int bad = (n_in == 14) ? -1 : 14;
  if (bad < 0)
    for (int i = 0; i < 14; ++i)
      if (in_sizes[i] != want[i]) { bad = i; break; }
  if (bad >= 0) { k_markf<<<1, 64, 0, stream>>>(outF, 1024.0f * (160.0f + (float)bad)); return; }
  if (ws_size < WS_NEED_BYTES) { k_markf<<<1, 64, 0, stream>>>(outF, 180224.0f); return; }

  k_conv_x<<<5120, 256, 0, stream>>>(Q, K, V, ws + OFF_QB, Kb, Vb);
  k_conv_w<<<448, 256, 0, stream>>>(Wq, Wk, Wv, Wo, ws + OFF_BQ, ws + OFF_BK, ws + OFF_BV, ws + OFF_BO);
  k_gemm<u16><<<dim3(32, 4), 256, 0, stream>>>(ws + OFF_QB, 512, ws + OFF_BQ, 512, bq, ws + OFF_QP, 512);
  k_gemm<u16><<<dim3(64, 4), 256, 0, stream>>>(Kb, 512, ws + OFF_BK, 512, bk, ws + OFF_KP, 512);
  k_gemm<u16><<<dim3(64, 4), 256, 0, stream>>>(Vb, 512, ws + OFF_BV, 512, bv, VP, 512);
  k_transpose<<<dim3(32, 32), 256, 0, stream>>>(VP, ws + OFF_VPT);
  k_attn<<<dim3(64, 4, 2), 512, 0, stream>>>(ws + OFF_QP, ws + OFF_KP, ws + OFF_VPT,
                                             aff, qb, kvm, wout, ws + OFF_AP);
  k_gemm<float><<<dim3(32, 2), 256, 0, stream>>>(ws + OFF_AP, 512, ws + OFF_BO, 512, bo, outF, 256);
}